// Round 6
// baseline (852.262 us; speedup 1.0000x reference)
//
#include <hip/hip_runtime.h>
#include <hip/hip_bf16.h>

#define BQ     131072
#define NT     5
#define ROWS   32            // batch rows per block (2 blocks/CU co-resident)

typedef unsigned short u16;
typedef unsigned int   u32;
typedef unsigned long long u64;
typedef __attribute__((ext_vector_type(8))) short bf16x8;
typedef __attribute__((ext_vector_type(4))) float f32x4;
typedef __attribute__((ext_vector_type(2))) float f32x2;

__device__ __forceinline__ u16 f2bf(float x) {
  union { float f; u32 u; } v; v.f = x;
  u32 r = (v.u + 0x7FFFu + ((v.u >> 16) & 1u)) >> 16;
  return (u16)r;
}

// fused: transpose f32 src[K][N] -> bf16 dst[NP][K] for all 4 weight matrices
__global__ __launch_bounds__(256) void transpose_cast_all(
    const float* __restrict__ s0, const float* __restrict__ s1,
    const float* __restrict__ s2, const float* __restrict__ s3,
    u16* __restrict__ d0, u16* __restrict__ d1,
    u16* __restrict__ d2, u16* __restrict__ d3) {
  __shared__ float tile[32][33];
  const int z = blockIdx.z;
  const float* src; u16* dst; int K, N, NP;
  if      (z == 0) { src = s0; dst = d0; K = 256; N = 512; NP = 512; }
  else if (z == 1) { src = s1; dst = d1; K = 512; N = 512; NP = 512; }
  else if (z == 2) { src = s2; dst = d2; K = 512; N = 512; NP = 512; }
  else             { src = s3; dst = d3; K = 512; N = 35;  NP = 48;  }
  int kx = blockIdx.x * 32, ny = blockIdx.y * 32;
  if (kx >= K || ny >= NP) return;
  int tx = threadIdx.x, ty = threadIdx.y;
#pragma unroll
  for (int i = 0; i < 4; i++) {
    int k = kx + ty + i * 8, n = ny + tx;
    tile[ty + i * 8][tx] = (k < K && n < N) ? src[(size_t)k * N + n] : 0.f;
  }
  __syncthreads();
#pragma unroll
  for (int i = 0; i < 4; i++) {
    int n = ny + ty + i * 8, k = kx + tx;
    if (n < NP && k < K) dst[(size_t)n * K + k] = f2bf(tile[tx][ty + i * 8]);
  }
}

// One fused layer: 8 waves, each owns 64 features x 32 batch rows.
// D[f][b] = sum_k WT[f][k]*act[b][k]; +bias; LayerNorm over f per b; act; bf16->dst.
// ACT: 0=none, 1=relu, 2=silu
template <int K, int ACT>
__device__ __forceinline__ void layer(
    const u16* __restrict__ wt, const float* __restrict__ bias,
    const float* __restrict__ gam, const float* __restrict__ bet,
    const u16* src, u16* dst, float* sStat,
    int lane, int wid, int l15, int lg, int wfb)
{
  f32x4 acc[4][2];   // [feat-16-tile][row-16-tile]
#pragma unroll
  for (int m = 0; m < 4; m++)
#pragma unroll
    for (int n = 0; n < 2; n++) acc[m][n] = (f32x4){0.f, 0.f, 0.f, 0.f};

  // bounded unroll: full unroll spills at the 128-VGPR / 4-waves-per-EU budget
#pragma unroll 2
  for (int kb = 0; kb < K; kb += 32) {
    const int k0 = kb + lg * 8;
    bf16x8 a[4];
#pragma unroll
    for (int m = 0; m < 4; m++)
      a[m] = *(const bf16x8*)(wt + (size_t)(wfb + m * 16 + l15) * K + k0);
    bf16x8 bv[2];
#pragma unroll
    for (int n = 0; n < 2; n++) {
      int b = n * 16 + l15;
      int byte = (b * (K * 2) + k0 * 2) ^ ((b & 7) << 4);
      bv[n] = *(const bf16x8*)((const char*)src + byte);
    }
    __builtin_amdgcn_s_setprio(1);
#pragma unroll
    for (int m = 0; m < 4; m++)
#pragma unroll
      for (int n = 0; n < 2; n++)
        acc[m][n] = __builtin_amdgcn_mfma_f32_16x16x32_bf16(a[m], bv[n], acc[m][n], 0, 0, 0);
    __builtin_amdgcn_s_setprio(0);
  }

  // bias add (f = wfb + m*16 + lg*4 + r)
#pragma unroll
  for (int m = 0; m < 4; m++) {
    f32x4 bv4 = *(const f32x4*)(bias + wfb + m * 16 + lg * 4);
#pragma unroll
    for (int n = 0; n < 2; n++)
#pragma unroll
      for (int r = 0; r < 4; r++) acc[m][n][r] += bv4[r];
  }

  // per-row partial stats over this wave's 64-feature slice
  float s[2], q[2];
#pragma unroll
  for (int n = 0; n < 2; n++) {
    s[n] = 0.f; q[n] = 0.f;
#pragma unroll
    for (int m = 0; m < 4; m++)
#pragma unroll
      for (int r = 0; r < 4; r++) { float v = acc[m][n][r]; s[n] += v; q[n] += v * v; }
    s[n] += __shfl_xor(s[n], 16); q[n] += __shfl_xor(q[n], 16);
    s[n] += __shfl_xor(s[n], 32); q[n] += __shfl_xor(q[n], 32);
  }
  // partials: sStat[w][b] f32x2 -> float idx = w*64 + b*2
  if (lg == 0) {
#pragma unroll
    for (int n = 0; n < 2; n++) {
      int b = n * 16 + l15;
      *(f32x2*)(sStat + wid * 64 + b * 2) = (f32x2){s[n], q[n]};
    }
  }
  __syncthreads();

  // every lane combines the 8 partials for row b = lane&31 (upper half duplicates: broadcast)
  const int br = lane & 31;
  float ss = 0.f, qq = 0.f;
#pragma unroll
  for (int w = 0; w < 8; w++) {
    f32x2 v = *(const f32x2*)(sStat + w * 64 + br * 2);
    ss += v[0]; qq += v[1];
  }
  float meanb = ss * (1.f / 512.f);
  float rstdb = rsqrtf(qq * (1.f / 512.f) - meanb * meanb + 1e-5f);

  float mean[2], rstd[2];
#pragma unroll
  for (int n = 0; n < 2; n++) {
    mean[n] = __shfl(meanb, n * 16 + l15);
    rstd[n] = __shfl(rstdb, n * 16 + l15);
  }

#pragma unroll
  for (int m = 0; m < 4; m++) {
    int f0 = wfb + m * 16 + lg * 4;
    f32x4 gv  = *(const f32x4*)(gam + f0);
    f32x4 bev = *(const f32x4*)(bet + f0);
#pragma unroll
    for (int n = 0; n < 2; n++) {
      int b = n * 16 + l15;
      u16 pk[4];
#pragma unroll
      for (int r = 0; r < 4; r++) {
        float v = (acc[m][n][r] - mean[n]) * rstd[n] * gv[r] + bev[r];
        if (ACT == 1) v = fmaxf(v, 0.f);
        else if (ACT == 2) v = v / (1.f + __expf(-v));
        pk[r] = f2bf(v);
      }
      u64 w64 = (u64)pk[0] | ((u64)pk[1] << 16) | ((u64)pk[2] << 32) | ((u64)pk[3] << 48);
      int byte = (b * 1024 + f0 * 2) ^ ((b & 7) << 4);
      *(u64*)((char*)dst + byte) = w64;
    }
  }
  __syncthreads();
}

__global__ __launch_bounds__(512, 4) void ifs_main(
    const float* __restrict__ z,
    const u16* __restrict__ wt1, const u16* __restrict__ wta,
    const u16* __restrict__ wtb, const u16* __restrict__ wtout,
    const float* __restrict__ b1, const float* __restrict__ g1, const float* __restrict__ be1,
    const float* __restrict__ ba, const float* __restrict__ ga, const float* __restrict__ bea,
    const float* __restrict__ bb, const float* __restrict__ gb, const float* __restrict__ beb,
    const float* __restrict__ bout, float* __restrict__ out)
{
  // 32 rows: sA 32KB + sB 32KB + stats 2KB = 66KB -> 2 blocks/CU (phase overlap)
  __shared__ __align__(16) char smem[32768 * 2 + 2048];
  u16*   sA    = (u16*)smem;                 // h
  u16*   sB    = (u16*)(smem + 32768);       // z -> y1 -> y
  float* sStat = (float*)(smem + 65536);     // [8][32] f32x2 partial stats

  const int tid  = threadIdx.x;
  const int lane = tid & 63, wid = tid >> 6;
  const int l15  = lane & 15, lg = lane >> 4;
  const int bbase = blockIdx.x * ROWS;
  const int wfb   = wid * 64;

  // ---- stage z tile: f32 -> bf16 [32][256], swizzled
#pragma unroll
  for (int i = 0; i < 4; i++) {
    int c = tid + i * 512;                   // c in [0, 2048)
    int b = c >> 6, kc = c & 63;
    const float4 v = *(const float4*)(z + (size_t)(bbase + b) * 256 + kc * 4);
    u32 lo = (u32)f2bf(v.x) | ((u32)f2bf(v.y) << 16);
    u32 hi = (u32)f2bf(v.z) | ((u32)f2bf(v.w) << 16);
    u64 pk = (u64)lo | ((u64)hi << 32);
    int byte = (b * 512 + kc * 8) ^ ((b & 7) << 4);
    *(u64*)((char*)sB + byte) = pk;
  }
  __syncthreads();

  // ---- 3 fused GEMM+LN layers
  layer<256, 1>(wt1, b1, g1, be1, sB, sA, sStat, lane, wid, l15, lg, wfb); // h
  layer<512, 2>(wta, ba, ga, bea, sA, sB, sStat, lane, wid, l15, lg, wfb); // y1
  layer<512, 0>(wtb, bb, gb, beb, sB, sB, sStat, lane, wid, l15, lg, wfb); // y

  // ---- head GEMM: x = h@Wout + y@Wout, K split 4 ways across waves
  {
    const int nf = wid & 1, kh = wid >> 1;   // nf: row-16-tile, kh: K-quarter
    const int b  = nf * 16 + l15;
    f32x4 xacc[3];
#pragma unroll
    for (int m = 0; m < 3; m++) xacc[m] = (f32x4){0.f, 0.f, 0.f, 0.f};
#pragma unroll 2
    for (int kk = 0; kk < 128; kk += 32) {
      int k0 = kh * 128 + kk + lg * 8;
      int byte = (b * 1024 + k0 * 2) ^ ((b & 7) << 4);
      bf16x8 bh = *(const bf16x8*)((const char*)sA + byte);
      bf16x8 by = *(const bf16x8*)((const char*)sB + byte);
#pragma unroll
      for (int m = 0; m < 3; m++) {
        bf16x8 aw = *(const bf16x8*)(wtout + (size_t)(m * 16 + l15) * 512 + k0);
        xacc[m] = __builtin_amdgcn_mfma_f32_16x16x32_bf16(aw, bh, xacc[m], 0, 0, 0);
        xacc[m] = __builtin_amdgcn_mfma_f32_16x16x32_bf16(aw, by, xacc[m], 0, 0, 0);
      }
    }
    __syncthreads();                       // all reads of sA/sB complete
    float* sP = (float*)sA;                // [4][32][48] partials (24 KB)
#pragma unroll
    for (int m = 0; m < 3; m++)
      *(f32x4*)(sP + (size_t)(kh * 32 + b) * 48 + m * 16 + lg * 4) = xacc[m];
    __syncthreads();
    float* sX = (float*)sB;                // [32][48] final x (6 KB)
    if (tid < 384) {
      int b2 = tid / 12, j = (tid - b2 * 12) * 4;
      f32x4 v0 = *(const f32x4*)(sP + (size_t)(0 * 32 + b2) * 48 + j);
      f32x4 v1 = *(const f32x4*)(sP + (size_t)(1 * 32 + b2) * 48 + j);
      f32x4 v2 = *(const f32x4*)(sP + (size_t)(2 * 32 + b2) * 48 + j);
      f32x4 v3 = *(const f32x4*)(sP + (size_t)(3 * 32 + b2) * 48 + j);
#pragma unroll
      for (int r = 0; r < 4; r++) v0[r] += v1[r] + v2[r] + v3[r];
      *(f32x4*)(sX + (size_t)b2 * 48 + j) = v0;
    }
    __syncthreads();

    // ---- epilogue: softmax over 5 logits; analytic 2x2 SVD clamp per (b, t)
    if (tid < ROWS) {
      int bb2 = tid;
      float l[5], mx = -1e30f;
#pragma unroll
      for (int j = 0; j < 5; j++) { l[j] = sX[bb2 * 48 + 30 + j] + bout[30 + j]; mx = fmaxf(mx, l[j]); }
      float ssum = 0.f, e[5];
#pragma unroll
      for (int j = 0; j < 5; j++) { e[j] = __expf(l[j] - mx); ssum += e[j]; }
      float inv = 1.f / ssum;
      float* op = out + (size_t)BQ * 30 + (size_t)(bbase + bb2) * 5;
#pragma unroll
      for (int j = 0; j < 5; j++) op[j] = e[j] * inv;
    }
    if (tid < ROWS * NT) {
      int b2 = tid / 5, t = tid - b2 * 5;
      const float* xr = sX + b2 * 48 + t * 6;
      float a   = xr[0] + bout[t * 6 + 0];
      float bb_ = xr[1] + bout[t * 6 + 1];
      float tx  = xr[2] + bout[t * 6 + 2];
      float c   = xr[3] + bout[t * 6 + 3];
      float d   = xr[4] + bout[t * 6 + 4];
      float ty  = xr[5] + bout[t * 6 + 5];
      float E = 0.5f * (a + d), F = 0.5f * (a - d);
      float G = 0.5f * (c + bb_), H = 0.5f * (c - bb_);
      float Q = sqrtf(E * E + H * H), R = sqrtf(F * F + G * G);
      float sx = Q + R, sy = Q - R;
      float a1 = atan2f(G, F), a2 = atan2f(H, E);
      float th = 0.5f * (a2 - a1), ph = 0.5f * (a2 + a1);
      float sxc = fminf(sx, 0.9f);
      float syc = fminf(fmaxf(sy, -0.9f), 0.9f);
      float st, ct, sp, cp;
      __sincosf(th, &st, &ct);
      __sincosf(ph, &sp, &cp);
      float ux = cp * sxc, uy = sp * sxc, vx = sp * syc, vy = cp * syc;
      float m00 =  ux * ct - vx * st;
      float m01 = -ux * st - vx * ct;
      float m10 =  uy * ct + vy * st;
      float m11 = -uy * st + vy * ct;
      float* op = out + (size_t)(bbase + b2) * 30 + t * 6;
      op[0] = m00; op[1] = m01; op[2] = tx;
      op[3] = m10; op[4] = m11; op[5] = ty;
    }
  }
}

extern "C" void kernel_launch(void* const* d_in, const int* in_sizes, int n_in,
                              void* d_out, int out_size, void* d_ws, size_t ws_size,
                              hipStream_t stream) {
  const float* z    = (const float*)d_in[0];
  const float* W1   = (const float*)d_in[1];
  const float* b1   = (const float*)d_in[2];
  const float* g1   = (const float*)d_in[3];
  const float* be1  = (const float*)d_in[4];
  const float* Wa   = (const float*)d_in[5];
  const float* ba   = (const float*)d_in[6];
  const float* ga   = (const float*)d_in[7];
  const float* bea  = (const float*)d_in[8];
  const float* Wb   = (const float*)d_in[9];
  const float* bb   = (const float*)d_in[10];
  const float* gb   = (const float*)d_in[11];
  const float* beb  = (const float*)d_in[12];
  const float* Wout = (const float*)d_in[13];
  const float* bout = (const float*)d_in[14];
  float* out = (float*)d_out;

  char* w = (char*)d_ws;
  u16* wt1   = (u16*)(w);
  u16* wta   = (u16*)(w + 262144);
  u16* wtb   = (u16*)(w + 786432);
  u16* wtout = (u16*)(w + 1310720);

  transpose_cast_all<<<dim3(16, 16, 4), dim3(32, 8), 0, stream>>>(
      W1, Wa, Wb, Wout, wt1, wta, wtb, wtout);

  ifs_main<<<BQ / ROWS, 512, 0, stream>>>(
      z, wt1, wta, wtb, wtout,
      b1, g1, be1, ba, ga, bea, bb, gb, beb, bout, out);
}

// Round 9
// 734.960 us; speedup vs baseline: 1.1596x; 1.1596x over previous
//
#include <hip/hip_runtime.h>
#include <hip/hip_bf16.h>

#define BQ 131072
#define NT 5

typedef unsigned short u16;
typedef unsigned int   u32;
typedef unsigned long long u64;
typedef __attribute__((ext_vector_type(8))) short bf16x8;
typedef __attribute__((ext_vector_type(4))) float f32x4;
typedef __attribute__((ext_vector_type(2))) float f32x2;

// ---- LDS layout (bytes) ----
#define ACT_OFF   0          // 64 KB activations [64 rows][512] bf16 (z occupies [64][256])
#define WBUF_OFF  65536      // 64 KB: 2x32KB weight slabs; head reuses as sP[4][64][52] f32
#define SX_OFF    (WBUF_OFF + 53248)  // [64][48] f32 final x (fits: 53248+12288=65536)
#define XH_OFF    131072     // 12 KB [64][48] f32  (h @ Wout partial result)
#define STAT_OFF  143360     // 8 KB [16][64] f32x2 LN partial stats
#define SMEM_SZ   151552

__device__ __forceinline__ u16 f2bf(float x) {
  union { float f; u32 u; } v; v.f = x;
  u32 r = (v.u + 0x7FFFu + ((v.u >> 16) & 1u)) >> 16;
  return (u16)r;
}

// weight-slab element byte offset (within one 32KB slab), XOR-swizzled so the
// 64-lane ds_read_b128 of A-fragments is bank-conflict-free (2 lanes/16B group)
__device__ __forceinline__ int wsw(int f, int k) {  // f in [0,512), k in [0,32)
  return (f * 64 + k * 2) ^ ((f & 7) << 4);
}

// ---- prep: weights -> bf16 workspace.
// z<3: pre-swizzled slab-major layout consumed by global_load_lds (linear DMA
//      dest == swizzled LDS layout, m173 pattern).
// z==3: Wout as linear [48][512] bf16 (feat-major), zero-padded feats >= 35.
__global__ __launch_bounds__(256) void prep_weights(
    const float* __restrict__ s0, const float* __restrict__ s1,
    const float* __restrict__ s2, const float* __restrict__ s3,
    u16* __restrict__ d0, u16* __restrict__ d1,
    u16* __restrict__ d2, u16* __restrict__ d3) {
  const int zid = blockIdx.z;
  int kx = blockIdx.x * 32, ny = blockIdx.y * 32;
  int tx = threadIdx.x, ty = threadIdx.y;
  if (zid < 3) {
    const float* src = (zid == 0) ? s0 : ((zid == 1) ? s1 : s2);
    u16* dst         = (zid == 0) ? d0 : ((zid == 1) ? d1 : d2);
    const int K = (zid == 0) ? 256 : 512;
    if (kx >= K) return;
#pragma unroll
    for (int i = 0; i < 4; i++) {
      int k = kx + ty + i * 8, n = ny + tx;
      if (k < K) {
        u16 v = f2bf(src[(size_t)k * 512 + n]);
        size_t byte = (size_t)(k >> 5) * 32768 + (u32)wsw(n, k & 31);
        *(u16*)((char*)dst + byte) = v;
      }
    }
  } else {
    if (ny >= 48) return;
    __shared__ float tile[32][33];
#pragma unroll
    for (int i = 0; i < 4; i++) {
      int k = kx + ty + i * 8, n = ny + tx;
      tile[ty + i * 8][tx] = (k < 512 && n < 35) ? s3[(size_t)k * 35 + n] : 0.f;
    }
    __syncthreads();
#pragma unroll
    for (int i = 0; i < 4; i++) {
      int n = ny + ty + i * 8, k = kx + tx;
      if (n < 48) d3[(size_t)n * 512 + k] = f2bf(tile[tx][ty + i * 8]);
    }
  }
}

// stage one 32KB weight slab: 16 waves x 2 async 1KB DMAs (global -> LDS)
__device__ __forceinline__ void stage_slab(const u16* __restrict__ wsrc,
                                           char* ldsdst, int wid, int lane) {
#pragma unroll
  for (int i = 0; i < 2; i++) {
    int off = (wid * 2 + i) * 1024;
    __builtin_amdgcn_global_load_lds(
        (const __attribute__((address_space(1))) void*)((const char*)wsrc + off + lane * 16),
        (__attribute__((address_space(3))) void*)(ldsdst + off), 16, 0, 0);
  }
}

// One fused layer: 16 waves, each owns 32 features x 64 rows. Weights streamed
// through LDS (double-buffered 32KB slabs, async DMA, drain per K-step).
// ACT: 0=none, 1=relu, 2=silu. In-place (src==dst) safe: all K-loop reads
// complete before the post-stats barrier that precedes epilogue writes.
template <int K, int ACT>
__device__ __forceinline__ void layer(
    const u16* __restrict__ wslabs, const float* __restrict__ bias,
    const float* __restrict__ gam, const float* __restrict__ bet,
    const char* src, char* dst, char* smem,
    int tid, int lane, int wid, int l15, int lg, int wfb)
{
  char* wbuf   = smem + WBUF_OFF;
  float* sStat = (float*)(smem + STAT_OFF);
  const int SS = (K == 256) ? 512 : 1024;   // src row stride (bytes)

  f32x4 acc[2][4];
#pragma unroll
  for (int m = 0; m < 2; m++)
#pragma unroll
    for (int n = 0; n < 4; n++) acc[m][n] = (f32x4){0.f, 0.f, 0.f, 0.f};

  // prologue: stage slab 0, wait, barrier
  stage_slab(wslabs, wbuf, wid, lane);
  asm volatile("s_waitcnt vmcnt(0)" ::: "memory");
  __syncthreads();

  const int aoff0 = wsw(wfb + l15, lg * 8);
  const int aoff1 = wsw(wfb + 16 + l15, lg * 8);
  const int NS = K / 32;
  for (int t = 0; t < NS; ++t) {
    const char* slab = wbuf + (t & 1) * 32768;
    if (t + 1 < NS)
      stage_slab(wslabs + (size_t)(t + 1) * 16384, wbuf + ((t + 1) & 1) * 32768, wid, lane);
    const int k0 = t * 32 + lg * 8;
    bf16x8 a0 = *(const bf16x8*)(slab + aoff0);
    bf16x8 a1 = *(const bf16x8*)(slab + aoff1);
    bf16x8 bv[4];
#pragma unroll
    for (int n = 0; n < 4; n++) {
      int b = n * 16 + l15;
      int byte = (b * SS + k0 * 2) ^ ((b & 7) << 4);
      bv[n] = *(const bf16x8*)(src + byte);
    }
    __builtin_amdgcn_s_setprio(1);
#pragma unroll
    for (int n = 0; n < 4; n++) {
      acc[0][n] = __builtin_amdgcn_mfma_f32_16x16x32_bf16(a0, bv[n], acc[0][n], 0, 0, 0);
      acc[1][n] = __builtin_amdgcn_mfma_f32_16x16x32_bf16(a1, bv[n], acc[1][n], 0, 0, 0);
    }
    __builtin_amdgcn_s_setprio(0);
    asm volatile("s_waitcnt vmcnt(0)" ::: "memory");
    __syncthreads();
  }

  // bias add (f = wfb + m*16 + lg*4 + r)
#pragma unroll
  for (int m = 0; m < 2; m++) {
    f32x4 bv4 = *(const f32x4*)(bias + wfb + m * 16 + lg * 4);
#pragma unroll
    for (int n = 0; n < 4; n++)
#pragma unroll
      for (int r = 0; r < 4; r++) acc[m][n][r] += bv4[r];
  }

  // per-row partial stats over this wave's 32-feature slice
  float s[4], q[4];
#pragma unroll
  for (int n = 0; n < 4; n++) {
    s[n] = 0.f; q[n] = 0.f;
#pragma unroll
    for (int m = 0; m < 2; m++)
#pragma unroll
      for (int r = 0; r < 4; r++) { float v = acc[m][n][r]; s[n] += v; q[n] += v * v; }
    s[n] += __shfl_xor(s[n], 16); q[n] += __shfl_xor(q[n], 16);
    s[n] += __shfl_xor(s[n], 32); q[n] += __shfl_xor(q[n], 32);
  }
  if (lg == 0) {
#pragma unroll
    for (int n = 0; n < 4; n++) {
      int b = n * 16 + l15;
      *(f32x2*)(sStat + wid * 128 + b * 2) = (f32x2){s[n], q[n]};
    }
  }
  __syncthreads();

  // every lane combines the 16 partials for row b = lane
  float ss = 0.f, qq = 0.f;
#pragma unroll
  for (int w = 0; w < 16; w++) {
    f32x2 v = *(const f32x2*)(sStat + w * 128 + lane * 2);
    ss += v[0]; qq += v[1];
  }
  float meanb = ss * (1.f / 512.f);
  float rstdb = rsqrtf(qq * (1.f / 512.f) - meanb * meanb + 1e-5f);

  float mean[4], rstd[4];
#pragma unroll
  for (int n = 0; n < 4; n++) {
    mean[n] = __shfl(meanb, n * 16 + l15);
    rstd[n] = __shfl(rstdb, n * 16 + l15);
  }

#pragma unroll
  for (int m = 0; m < 2; m++) {
    int f0 = wfb + m * 16 + lg * 4;
    f32x4 gv  = *(const f32x4*)(gam + f0);
    f32x4 bev = *(const f32x4*)(bet + f0);
#pragma unroll
    for (int n = 0; n < 4; n++) {
      int b = n * 16 + l15;
      u16 pk[4];
#pragma unroll
      for (int r = 0; r < 4; r++) {
        float v = (acc[m][n][r] - mean[n]) * rstd[n] * gv[r] + bev[r];
        if (ACT == 1) v = fmaxf(v, 0.f);
        else if (ACT == 2) v = v / (1.f + __expf(-v));
        pk[r] = f2bf(v);
      }
      u64 w64 = (u64)pk[0] | ((u64)pk[1] << 16) | ((u64)pk[2] << 32) | ((u64)pk[3] << 48);
      int byte = (b * 1024 + f0 * 2) ^ ((b & 7) << 4);
      *(u64*)(dst + byte) = w64;
    }
  }
  __syncthreads();
}

// head GEMM pass: partials = act @ Wout (K split 4-way over waves), reduce.
// FINAL=false: reduce -> sXh.  FINAL=true: reduce + sXh -> sX.
template <bool FINAL>
__device__ __forceinline__ void head_pass(
    const u16* __restrict__ wtout, const char* act, char* smem,
    int tid, int wid, int l15, int lg)
{
  float* sP  = (float*)(smem + WBUF_OFF);   // [4][64][52] f32 (stride 52: bank spread)
  float* sXh = (float*)(smem + XH_OFF);
  float* sX  = FINAL ? (float*)(smem + SX_OFF) : sXh;
  const int nf = wid & 3, kh = wid >> 2;
  const int b  = nf * 16 + l15;
  f32x4 xacc[3];
#pragma unroll
  for (int m = 0; m < 3; m++) xacc[m] = (f32x4){0.f, 0.f, 0.f, 0.f};
#pragma unroll
  for (int kk = 0; kk < 128; kk += 32) {
    int k0 = kh * 128 + kk + lg * 8;
    int byte = (b * 1024 + k0 * 2) ^ ((b & 7) << 4);
    bf16x8 bh = *(const bf16x8*)(act + byte);
#pragma unroll
    for (int m = 0; m < 3; m++) {
      bf16x8 aw = *(const bf16x8*)(wtout + (size_t)(m * 16 + l15) * 512 + k0);
      xacc[m] = __builtin_amdgcn_mfma_f32_16x16x32_bf16(aw, bh, xacc[m], 0, 0, 0);
    }
  }
  // wbuf is free here (previous layer fully drained its DMAs + barriers)
#pragma unroll
  for (int m = 0; m < 3; m++)
    *(f32x4*)(sP + (size_t)(kh * 64 + b) * 52 + m * 16 + lg * 4) = xacc[m];
  __syncthreads();
  if (tid < 768) {
    int b2 = tid / 12, j = (tid - b2 * 12) * 4;
    f32x4 v0 = *(const f32x4*)(sP + (size_t)(0 * 64 + b2) * 52 + j);
    f32x4 v1 = *(const f32x4*)(sP + (size_t)(1 * 64 + b2) * 52 + j);
    f32x4 v2 = *(const f32x4*)(sP + (size_t)(2 * 64 + b2) * 52 + j);
    f32x4 v3 = *(const f32x4*)(sP + (size_t)(3 * 64 + b2) * 52 + j);
#pragma unroll
    for (int r = 0; r < 4; r++) v0[r] += v1[r] + v2[r] + v3[r];
    if (FINAL) {
      f32x4 vh = *(const f32x4*)(sXh + (size_t)b2 * 48 + j);
#pragma unroll
      for (int r = 0; r < 4; r++) v0[r] += vh[r];
    }
    *(f32x4*)(sX + (size_t)b2 * 48 + j) = v0;
  }
  __syncthreads();
}

__global__ __launch_bounds__(1024) void ifs_main(
    const float* __restrict__ z,
    const u16* __restrict__ wt1, const u16* __restrict__ wta,
    const u16* __restrict__ wtb, const u16* __restrict__ wtout,
    const float* __restrict__ b1, const float* __restrict__ g1, const float* __restrict__ be1,
    const float* __restrict__ ba, const float* __restrict__ ga, const float* __restrict__ bea,
    const float* __restrict__ bb, const float* __restrict__ gb, const float* __restrict__ beb,
    const float* __restrict__ bout, float* __restrict__ out)
{
  __shared__ __align__(16) char smem[SMEM_SZ];
  const int tid  = threadIdx.x;
  const int lane = tid & 63, wid = tid >> 6;
  const int l15  = lane & 15, lg = lane >> 4;
  const int bbase = blockIdx.x * 64;
  const int wfb   = wid * 32;
  char* act = smem + ACT_OFF;

  // ---- stage z tile: f32 -> bf16 [64][256], swizzled
#pragma unroll
  for (int i = 0; i < 4; i++) {
    int c = tid + i * 1024;
    int b = c >> 6, kc = c & 63;
    const float4 v = *(const float4*)(z + (size_t)(bbase + b) * 256 + kc * 4);
    u32 lo = (u32)f2bf(v.x) | ((u32)f2bf(v.y) << 16);
    u32 hi = (u32)f2bf(v.z) | ((u32)f2bf(v.w) << 16);
    u64 pk = (u64)lo | ((u64)hi << 32);
    int byte = (b * 512 + kc * 8) ^ ((b & 7) << 4);
    *(u64*)(act + byte) = pk;
  }
  __syncthreads();

  // ---- fused pipeline (single in-place activation buffer)
  layer<256, 1>(wt1, b1, g1, be1, act, act, smem, tid, lane, wid, l15, lg, wfb); // z -> h
  head_pass<false>(wtout, act, smem, tid, wid, l15, lg);                         // xh = h@Wout
  layer<512, 2>(wta, ba, ga, bea, act, act, smem, tid, lane, wid, l15, lg, wfb); // h -> y1
  layer<512, 0>(wtb, bb, gb, beb, act, act, smem, tid, lane, wid, l15, lg, wfb); // y1 -> y
  head_pass<true>(wtout, act, smem, tid, wid, l15, lg);                          // sX = xh + y@Wout

  // ---- epilogue: softmax over 5 logits; analytic 2x2 SVD clamp per (b, t)
  float* sX = (float*)(smem + SX_OFF);
  if (tid < 64) {
    int bb2 = tid;
    float l[5], mx = -1e30f;
#pragma unroll
    for (int j = 0; j < 5; j++) { l[j] = sX[bb2 * 48 + 30 + j] + bout[30 + j]; mx = fmaxf(mx, l[j]); }
    float ssum = 0.f, e[5];
#pragma unroll
    for (int j = 0; j < 5; j++) { e[j] = __expf(l[j] - mx); ssum += e[j]; }
    float inv = 1.f / ssum;
    float* op = out + (size_t)BQ * 30 + (size_t)(bbase + bb2) * 5;
#pragma unroll
    for (int j = 0; j < 5; j++) op[j] = e[j] * inv;
  }
  if (tid < 320) {
    int b2 = tid / 5, t = tid - b2 * 5;
    const float* xr = sX + b2 * 48 + t * 6;
    float a   = xr[0] + bout[t * 6 + 0];
    float bb_ = xr[1] + bout[t * 6 + 1];
    float tx  = xr[2] + bout[t * 6 + 2];
    float c   = xr[3] + bout[t * 6 + 3];
    float d   = xr[4] + bout[t * 6 + 4];
    float ty  = xr[5] + bout[t * 6 + 5];
    float E = 0.5f * (a + d), F = 0.5f * (a - d);
    float G = 0.5f * (c + bb_), H = 0.5f * (c - bb_);
    float Q = sqrtf(E * E + H * H), R = sqrtf(F * F + G * G);
    float sx = Q + R, sy = Q - R;
    float a1 = atan2f(G, F), a2 = atan2f(H, E);
    float th = 0.5f * (a2 - a1), ph = 0.5f * (a2 + a1);
    float sxc = fminf(sx, 0.9f);
    float syc = fminf(fmaxf(sy, -0.9f), 0.9f);
    float st, ct, sp, cp;
    __sincosf(th, &st, &ct);
    __sincosf(ph, &sp, &cp);
    float ux = cp * sxc, uy = sp * sxc, vx = sp * syc, vy = cp * syc;
    float m00 =  ux * ct - vx * st;
    float m01 = -ux * st - vx * ct;
    float m10 =  uy * ct + vy * st;
    float m11 = -uy * st + vy * ct;
    float* op = out + (size_t)(bbase + b2) * 30 + t * 6;
    op[0] = m00; op[1] = m01; op[2] = tx;
    op[3] = m10; op[4] = m11; op[5] = ty;
  }
}

extern "C" void kernel_launch(void* const* d_in, const int* in_sizes, int n_in,
                              void* d_out, int out_size, void* d_ws, size_t ws_size,
                              hipStream_t stream) {
  const float* z    = (const float*)d_in[0];
  const float* W1   = (const float*)d_in[1];
  const float* b1   = (const float*)d_in[2];
  const float* g1   = (const float*)d_in[3];
  const float* be1  = (const float*)d_in[4];
  const float* Wa   = (const float*)d_in[5];
  const float* ba   = (const float*)d_in[6];
  const float* ga   = (const float*)d_in[7];
  const float* bea  = (const float*)d_in[8];
  const float* Wb   = (const float*)d_in[9];
  const float* bb   = (const float*)d_in[10];
  const float* gb   = (const float*)d_in[11];
  const float* beb  = (const float*)d_in[12];
  const float* Wout = (const float*)d_in[13];
  const float* bout = (const float*)d_in[14];
  float* out = (float*)d_out;

  char* w = (char*)d_ws;
  u16* wt1   = (u16*)(w);             // 8 slabs  (256 KB)
  u16* wta   = (u16*)(w + 262144);    // 16 slabs (512 KB)
  u16* wtb   = (u16*)(w + 786432);    // 16 slabs (512 KB)
  u16* wtout = (u16*)(w + 1310720);   // [48][512] linear (48 KB)

  prep_weights<<<dim3(16, 16, 4), dim3(32, 8), 0, stream>>>(
      W1, Wa, Wb, Wout, wt1, wta, wtb, wtout);

  ifs_main<<<BQ / 64, 1024, 0, stream>>>(
      z, wt1, wta, wtb, wtout,
      b1, g1, be1, ba, ga, bea, bb, gb, beb, bout, out);
}

// Round 11
// 620.379 us; speedup vs baseline: 1.3738x; 1.1847x over previous
//
#include <hip/hip_runtime.h>
#include <hip/hip_bf16.h>

#define BQ 131072
#define NT 5

typedef unsigned short u16;
typedef unsigned int   u32;
typedef unsigned long long u64;
typedef __attribute__((ext_vector_type(8))) short bf16x8;
typedef __attribute__((ext_vector_type(4))) float f32x4;
typedef __attribute__((ext_vector_type(2))) float f32x2;

// ---- LDS layout (bytes) ----
#define ACT_OFF   0                      // 64 KB activations [64 rows][512] bf16
#define WBUF_OFF  65536                  // 64 KB: 2x32KB weight slabs; head reuses as sP
#define SX_OFF    (WBUF_OFF + 28672)     // [64][48] f32 final x (sP ends at 26.6KB)
#define XH_OFF    131072                 // 12 KB [64][48] f32 (h @ Wout partial)
#define STAT_OFF  143360                 // 4 KB [8][64] f32x2 LN partial stats
#define SMEM_SZ   147456

__device__ __forceinline__ u16 f2bf(float x) {
  union { float f; u32 u; } v; v.f = x;
  u32 r = (v.u + 0x7FFFu + ((v.u >> 16) & 1u)) >> 16;
  return (u16)r;
}

// weight-slab element byte offset (within one 32KB slab), XOR-swizzled so the
// 64-lane ds_read_b128 of A-fragments is bank-conflict-free
__device__ __forceinline__ int wsw(int f, int k) {  // f in [0,512), k in [0,32)
  return (f * 64 + k * 2) ^ ((f & 7) << 4);
}

// ---- prep: weights -> bf16 workspace (pre-swizzled slab-major; m173 pattern).
// z==3: Wout as linear [48][512] bf16, zero-padded feats >= 35.
__global__ __launch_bounds__(256) void prep_weights(
    const float* __restrict__ s0, const float* __restrict__ s1,
    const float* __restrict__ s2, const float* __restrict__ s3,
    u16* __restrict__ d0, u16* __restrict__ d1,
    u16* __restrict__ d2, u16* __restrict__ d3) {
  const int zid = blockIdx.z;
  int kx = blockIdx.x * 32, ny = blockIdx.y * 32;
  int tx = threadIdx.x, ty = threadIdx.y;
  if (zid < 3) {
    const float* src = (zid == 0) ? s0 : ((zid == 1) ? s1 : s2);
    u16* dst         = (zid == 0) ? d0 : ((zid == 1) ? d1 : d2);
    const int K = (zid == 0) ? 256 : 512;
    if (kx >= K) return;
#pragma unroll
    for (int i = 0; i < 4; i++) {
      int k = kx + ty + i * 8, n = ny + tx;
      if (k < K) {
        u16 v = f2bf(src[(size_t)k * 512 + n]);
        size_t byte = (size_t)(k >> 5) * 32768 + (u32)wsw(n, k & 31);
        *(u16*)((char*)dst + byte) = v;
      }
    }
  } else {
    if (ny >= 48) return;
    __shared__ float tile[32][33];
#pragma unroll
    for (int i = 0; i < 4; i++) {
      int k = kx + ty + i * 8, n = ny + tx;
      tile[ty + i * 8][tx] = (k < 512 && n < 35) ? s3[(size_t)k * 35 + n] : 0.f;
    }
    __syncthreads();
#pragma unroll
    for (int i = 0; i < 4; i++) {
      int n = ny + ty + i * 8, k = kx + tx;
      if (n < 48) d3[(size_t)n * 512 + k] = f2bf(tile[tx][ty + i * 8]);
    }
  }
}

// stage one 32KB weight slab: 8 waves x 4 async 1KB DMAs (global -> LDS)
__device__ __forceinline__ void stage_slab(const u16* __restrict__ wsrc,
                                           char* ldsdst, int wid, int lane) {
#pragma unroll
  for (int i = 0; i < 4; i++) {
    int off = (wid * 4 + i) * 1024;
    __builtin_amdgcn_global_load_lds(
        (const __attribute__((address_space(1))) void*)((const char*)wsrc + off + lane * 16),
        (__attribute__((address_space(3))) void*)(ldsdst + off), 16, 0, 0);
  }
}

// One fused layer: 8 waves, each owns 64 features x 64 rows. Weights streamed
// through LDS (double-buffered 32KB slabs, async DMA, drain per K-step).
// ACT: 0=none, 1=relu, 2=silu. In-place (src==dst) safe: all K-loop reads
// complete before the post-stats barrier that precedes the writes.
template <int K, int ACT>
__device__ __forceinline__ void layer(
    const u16* __restrict__ wslabs, const float* __restrict__ bias,
    const float* __restrict__ gam, const float* __restrict__ bet,
    const char* src, char* dst, char* smem,
    int tid, int lane, int wid, int l15, int lg, int wfb)
{
  char* wbuf   = smem + WBUF_OFF;
  float* sStat = (float*)(smem + STAT_OFF);
  const int SS = (K == 256) ? 512 : 1024;   // src row stride (bytes)

  f32x4 acc[4][4];
#pragma unroll
  for (int m = 0; m < 4; m++)
#pragma unroll
    for (int n = 0; n < 4; n++) acc[m][n] = (f32x4){0.f, 0.f, 0.f, 0.f};

  // prologue: stage slab 0, wait, barrier
  stage_slab(wslabs, wbuf, wid, lane);
  asm volatile("s_waitcnt vmcnt(0)" ::: "memory");
  __syncthreads();

  int aoff[4];
#pragma unroll
  for (int m = 0; m < 4; m++) aoff[m] = wsw(wfb + m * 16 + l15, lg * 8);

  const int NS = K / 32;
#pragma unroll 1
  for (int t = 0; t < NS; ++t) {
    const char* slab = wbuf + (t & 1) * 32768;
    if (t + 1 < NS)
      stage_slab(wslabs + (size_t)(t + 1) * 16384, wbuf + ((t + 1) & 1) * 32768, wid, lane);
    const int k0 = t * 32 + lg * 8;
    bf16x8 a[4];
#pragma unroll
    for (int m = 0; m < 4; m++) a[m] = *(const bf16x8*)(slab + aoff[m]);
    bf16x8 bv[4];
#pragma unroll
    for (int n = 0; n < 4; n++) {
      int b = n * 16 + l15;
      int byte = (b * SS + k0 * 2) ^ ((b & 7) << 4);
      bv[n] = *(const bf16x8*)(src + byte);
    }
    __builtin_amdgcn_s_setprio(1);
#pragma unroll
    for (int m = 0; m < 4; m++)
#pragma unroll
      for (int n = 0; n < 4; n++)
        acc[m][n] = __builtin_amdgcn_mfma_f32_16x16x32_bf16(a[m], bv[n], acc[m][n], 0, 0, 0);
    __builtin_amdgcn_s_setprio(0);
    asm volatile("s_waitcnt vmcnt(0)" ::: "memory");
    __syncthreads();
  }

  // bias add (f = wfb + m*16 + lg*4 + r)
#pragma unroll
  for (int m = 0; m < 4; m++) {
    f32x4 bv4 = *(const f32x4*)(bias + wfb + m * 16 + lg * 4);
#pragma unroll
    for (int n = 0; n < 4; n++)
#pragma unroll
      for (int r = 0; r < 4; r++) acc[m][n][r] += bv4[r];
  }

  // per-row partial stats over this wave's 64-feature slice
  float s[4], q[4];
#pragma unroll
  for (int n = 0; n < 4; n++) {
    s[n] = 0.f; q[n] = 0.f;
#pragma unroll
    for (int m = 0; m < 4; m++)
#pragma unroll
      for (int r = 0; r < 4; r++) { float v = acc[m][n][r]; s[n] += v; q[n] += v * v; }
    s[n] += __shfl_xor(s[n], 16); q[n] += __shfl_xor(q[n], 16);
    s[n] += __shfl_xor(s[n], 32); q[n] += __shfl_xor(q[n], 32);
  }
  if (lg == 0) {
#pragma unroll
    for (int n = 0; n < 4; n++) {
      int b = n * 16 + l15;
      *(f32x2*)(sStat + wid * 128 + b * 2) = (f32x2){s[n], q[n]};
    }
  }
  __syncthreads();

  // every lane combines the 8 partials for row b = lane
  float ss = 0.f, qq = 0.f;
#pragma unroll
  for (int w = 0; w < 8; w++) {
    f32x2 v = *(const f32x2*)(sStat + w * 128 + lane * 2);
    ss += v[0]; qq += v[1];
  }
  float meanb = ss * (1.f / 512.f);
  float rstdb = rsqrtf(qq * (1.f / 512.f) - meanb * meanb + 1e-5f);

  float mean[4], rstd[4];
#pragma unroll
  for (int n = 0; n < 4; n++) {
    mean[n] = __shfl(meanb, n * 16 + l15);
    rstd[n] = __shfl(rstdb, n * 16 + l15);
  }

#pragma unroll
  for (int m = 0; m < 4; m++) {
    int f0 = wfb + m * 16 + lg * 4;
    f32x4 gv  = *(const f32x4*)(gam + f0);
    f32x4 bev = *(const f32x4*)(bet + f0);
#pragma unroll
    for (int n = 0; n < 4; n++) {
      int b = n * 16 + l15;
      u16 pk[4];
#pragma unroll
      for (int r = 0; r < 4; r++) {
        float v = (acc[m][n][r] - mean[n]) * rstd[n] * gv[r] + bev[r];
        if (ACT == 1) v = fmaxf(v, 0.f);
        else if (ACT == 2) v = v / (1.f + __expf(-v));
        pk[r] = f2bf(v);
      }
      u64 w64 = (u64)pk[0] | ((u64)pk[1] << 16) | ((u64)pk[2] << 32) | ((u64)pk[3] << 48);
      int byte = (b * 1024 + f0 * 2) ^ ((b & 7) << 4);
      *(u64*)(dst + byte) = w64;
    }
  }
  __syncthreads();
}

// head GEMM pass: partials = act @ Wout (4 row-tiles x 2 K-halves over 8 waves).
// FINAL=false: reduce -> sXh.  FINAL=true: reduce + sXh -> sX.
template <bool FINAL>
__device__ __forceinline__ void head_pass(
    const u16* __restrict__ wtout, const char* act, char* smem,
    int tid, int wid, int l15, int lg)
{
  float* sP  = (float*)(smem + WBUF_OFF);   // [2][64][52] f32 (stride 52: bank spread)
  float* sXh = (float*)(smem + XH_OFF);
  float* sX  = FINAL ? (float*)(smem + SX_OFF) : sXh;
  const int nf = wid & 3, kh = wid >> 2;    // nf: row-16-tile, kh: K-half
  const int b  = nf * 16 + l15;
  f32x4 xacc[3];
#pragma unroll
  for (int m = 0; m < 3; m++) xacc[m] = (f32x4){0.f, 0.f, 0.f, 0.f};
#pragma unroll 1
  for (int kk = 0; kk < 256; kk += 32) {
    int k0 = kh * 256 + kk + lg * 8;
    int byte = (b * 1024 + k0 * 2) ^ ((b & 7) << 4);
    bf16x8 bh = *(const bf16x8*)(act + byte);
#pragma unroll
    for (int m = 0; m < 3; m++) {
      bf16x8 aw = *(const bf16x8*)(wtout + (size_t)(m * 16 + l15) * 512 + k0);
      xacc[m] = __builtin_amdgcn_mfma_f32_16x16x32_bf16(aw, bh, xacc[m], 0, 0, 0);
    }
  }
  // wbuf is free here (previous layer fully drained its DMAs + barriers)
#pragma unroll
  for (int m = 0; m < 3; m++)
    *(f32x4*)(sP + (size_t)(kh * 64 + b) * 52 + m * 16 + lg * 4) = xacc[m];
  __syncthreads();
  for (int idx = tid; idx < 768; idx += 512) {
    int b2 = idx / 12, j = (idx - b2 * 12) * 4;
    f32x4 v0 = *(const f32x4*)(sP + (size_t)(0 * 64 + b2) * 52 + j);
    f32x4 v1 = *(const f32x4*)(sP + (size_t)(1 * 64 + b2) * 52 + j);
#pragma unroll
    for (int r = 0; r < 4; r++) v0[r] += v1[r];
    if (FINAL) {
      f32x4 vh = *(const f32x4*)(sXh + (size_t)b2 * 48 + j);
#pragma unroll
      for (int r = 0; r < 4; r++) v0[r] += vh[r];
    }
    *(f32x4*)(sX + (size_t)b2 * 48 + j) = v0;
  }
  __syncthreads();
}

__global__ __launch_bounds__(512, 1) void ifs_main(
    const float* __restrict__ z,
    const u16* __restrict__ wt1, const u16* __restrict__ wta,
    const u16* __restrict__ wtb, const u16* __restrict__ wtout,
    const float* __restrict__ b1, const float* __restrict__ g1, const float* __restrict__ be1,
    const float* __restrict__ ba, const float* __restrict__ ga, const float* __restrict__ bea,
    const float* __restrict__ bb, const float* __restrict__ gb, const float* __restrict__ beb,
    const float* __restrict__ bout, float* __restrict__ out)
{
  __shared__ __align__(16) char smem[SMEM_SZ];
  const int tid  = threadIdx.x;
  const int lane = tid & 63, wid = tid >> 6;
  const int l15  = lane & 15, lg = lane >> 4;
  const int bbase = blockIdx.x * 64;
  const int wfb   = wid * 64;
  char* act = smem + ACT_OFF;

  // ---- stage z tile: f32 -> bf16 [64][256], swizzled.
  // 512 threads x 8 iters x 4 floats = 16384 = 64x256 (R10 bug: 4 iters = half tile)
#pragma unroll
  for (int i = 0; i < 8; i++) {
    int c = tid + i * 512;
    int b = c >> 6, kc = c & 63;
    const float4 v = *(const float4*)(z + (size_t)(bbase + b) * 256 + kc * 4);
    u32 lo = (u32)f2bf(v.x) | ((u32)f2bf(v.y) << 16);
    u32 hi = (u32)f2bf(v.z) | ((u32)f2bf(v.w) << 16);
    u64 pk = (u64)lo | ((u64)hi << 32);
    int byte = (b * 512 + kc * 8) ^ ((b & 7) << 4);
    *(u64*)(act + byte) = pk;
  }
  __syncthreads();

  // ---- fused pipeline (single in-place activation buffer)
  layer<256, 1>(wt1, b1, g1, be1, act, act, smem, tid, lane, wid, l15, lg, wfb); // z -> h
  head_pass<false>(wtout, act, smem, tid, wid, l15, lg);                         // xh = h@Wout
  layer<512, 2>(wta, ba, ga, bea, act, act, smem, tid, lane, wid, l15, lg, wfb); // h -> y1
  layer<512, 0>(wtb, bb, gb, beb, act, act, smem, tid, lane, wid, l15, lg, wfb); // y1 -> y
  head_pass<true>(wtout, act, smem, tid, wid, l15, lg);                          // sX = xh + y@Wout

  // ---- epilogue: softmax over 5 logits; analytic 2x2 SVD clamp per (b, t)
  float* sX = (float*)(smem + SX_OFF);
  if (tid < 64) {
    int bb2 = tid;
    float l[5], mx = -1e30f;
#pragma unroll
    for (int j = 0; j < 5; j++) { l[j] = sX[bb2 * 48 + 30 + j] + bout[30 + j]; mx = fmaxf(mx, l[j]); }
    float ssum = 0.f, e[5];
#pragma unroll
    for (int j = 0; j < 5; j++) { e[j] = __expf(l[j] - mx); ssum += e[j]; }
    float inv = 1.f / ssum;
    float* op = out + (size_t)BQ * 30 + (size_t)(bbase + bb2) * 5;
#pragma unroll
    for (int j = 0; j < 5; j++) op[j] = e[j] * inv;
  }
  if (tid < 320) {
    int b2 = tid / 5, t = tid - b2 * 5;
    const float* xr = sX + b2 * 48 + t * 6;
    float a   = xr[0] + bout[t * 6 + 0];
    float bb_ = xr[1] + bout[t * 6 + 1];
    float tx  = xr[2] + bout[t * 6 + 2];
    float c   = xr[3] + bout[t * 6 + 3];
    float d   = xr[4] + bout[t * 6 + 4];
    float ty  = xr[5] + bout[t * 6 + 5];
    float E = 0.5f * (a + d), F = 0.5f * (a - d);
    float G = 0.5f * (c + bb_), H = 0.5f * (c - bb_);
    float Q = sqrtf(E * E + H * H), R = sqrtf(F * F + G * G);
    float sx = Q + R, sy = Q - R;
    float a1 = atan2f(G, F), a2 = atan2f(H, E);
    float th = 0.5f * (a2 - a1), ph = 0.5f * (a2 + a1);
    float sxc = fminf(sx, 0.9f);
    float syc = fminf(fmaxf(sy, -0.9f), 0.9f);
    float st, ct, sp, cp;
    __sincosf(th, &st, &ct);
    __sincosf(ph, &sp, &cp);
    float ux = cp * sxc, uy = sp * sxc, vx = sp * syc, vy = cp * syc;
    float m00 =  ux * ct - vx * st;
    float m01 = -ux * st - vx * ct;
    float m10 =  uy * ct + vy * st;
    float m11 = -uy * st + vy * ct;
    float* op = out + (size_t)(bbase + b2) * 30 + t * 6;
    op[0] = m00; op[1] = m01; op[2] = tx;
    op[3] = m10; op[4] = m11; op[5] = ty;
  }
}

extern "C" void kernel_launch(void* const* d_in, const int* in_sizes, int n_in,
                              void* d_out, int out_size, void* d_ws, size_t ws_size,
                              hipStream_t stream) {
  const float* z    = (const float*)d_in[0];
  const float* W1   = (const float*)d_in[1];
  const float* b1   = (const float*)d_in[2];
  const float* g1   = (const float*)d_in[3];
  const float* be1  = (const float*)d_in[4];
  const float* Wa   = (const float*)d_in[5];
  const float* ba   = (const float*)d_in[6];
  const float* ga   = (const float*)d_in[7];
  const float* bea  = (const float*)d_in[8];
  const float* Wb   = (const float*)d_in[9];
  const float* bb   = (const float*)d_in[10];
  const float* gb   = (const float*)d_in[11];
  const float* beb  = (const float*)d_in[12];
  const float* Wout = (const float*)d_in[13];
  const float* bout = (const float*)d_in[14];
  float* out = (float*)d_out;

  char* w = (char*)d_ws;
  u16* wt1   = (u16*)(w);             // 8 slabs  (256 KB)
  u16* wta   = (u16*)(w + 262144);    // 16 slabs (512 KB)
  u16* wtb   = (u16*)(w + 786432);    // 16 slabs (512 KB)
  u16* wtout = (u16*)(w + 1310720);   // [48][512] linear (48 KB)

  prep_weights<<<dim3(16, 16, 4), dim3(32, 8), 0, stream>>>(
      W1, Wa, Wb, Wout, wt1, wta, wtb, wtout);

  ifs_main<<<BQ / 64, 512, 0, stream>>>(
      z, wt1, wta, wtb, wtout,
      b1, g1, be1, ba, ga, bea, bb, gb, beb, bout, out);
}